// Round 1
// baseline (202.938 us; speedup 1.0000x reference)
//
#include <hip/hip_runtime.h>
#include <stdint.h>
#include <stddef.h>

#define DEV __device__ __forceinline__

typedef __attribute__((ext_vector_type(4))) float f32x4;
typedef __attribute__((ext_vector_type(8))) short bf16x8;

union FragU { bf16x8 f; uint32_t u[4]; };

DEV uint32_t pk_bf16(float a, float b) {
  uint32_t d;
  asm("v_cvt_pk_bf16_f32 %0, %1, %2" : "=v"(d) : "v"(a), "v"(b));
  return d;
}

DEV uint16_t f2bf(float x) {  // round-to-nearest-even
  uint32_t u = __float_as_uint(x);
  u += 0x7fffu + ((u >> 16) & 1u);
  return (uint16_t)(u >> 16);
}

// ---------------------------------------------------------------------------
// K_pre: block 0..2: transpose Wq/Wk/Wv; block 3: Ww1/Ww2 -> bf16;
//        block 4: analytic BN1 stats -> a1[t] = g_p*rsqrt(var+eps)
// ---------------------------------------------------------------------------
__launch_bounds__(256)
__global__ void kpre(const float* __restrict__ Wq, const float* __restrict__ Wk,
                     const float* __restrict__ Wv, const float* __restrict__ Ww1,
                     const float* __restrict__ Ww2, const float* __restrict__ pos,
                     const float* __restrict__ Wp1, const float* __restrict__ g_p,
                     float* __restrict__ WqT, float* __restrict__ WkT,
                     float* __restrict__ WvT, uint16_t* __restrict__ W1bf,
                     uint16_t* __restrict__ W2bf, float* __restrict__ a1out) {
  const int bid = blockIdx.x, t = threadIdx.x;
  if (bid < 3) {
    const float* src = (bid == 0) ? Wq : ((bid == 1) ? Wk : Wv);
    float* dst = (bid == 0) ? WqT : ((bid == 1) ? WkT : WvT);
    for (int idx = t; idx < 4096; idx += 256) {
      int kk = idx >> 6, c = idx & 63;
      dst[kk * 64 + c] = src[c * 64 + kk];
    }
  } else if (bid == 3) {
    for (int idx = t; idx < 8192; idx += 256) {
      if (idx < 4096) W1bf[idx] = f2bf(Ww1[idx]);
      else            W2bf[idx - 4096] = f2bf(Ww2[idx - 4096]);
    }
  } else {
    __shared__ float acc9[2][9];
    __shared__ float red[256][10];
    for (int b = 0; b < 2; ++b) {
      float s[9];
#pragma unroll
      for (int a = 0; a < 9; ++a) s[a] = 0.f;
      for (int r = 0; r < 2; ++r) {
        int i = t + 256 * r;
        const float* p = pos + (size_t)(b * 512 + i) * 3;
        float p0 = p[0], p1 = p[1], p2 = p[2];
        s[0] += p0; s[1] += p1; s[2] += p2;
        s[3] += p0 * p0; s[4] += p0 * p1; s[5] += p0 * p2;
        s[6] += p1 * p1; s[7] += p1 * p2; s[8] += p2 * p2;
      }
#pragma unroll
      for (int a = 0; a < 9; ++a) red[t][a] = s[a];
      __syncthreads();
      if (t < 9) {
        float vsum = 0.f;
        for (int qq = 0; qq < 256; ++qq) vsum += red[qq][t];
        acc9[b][t] = vsum;
      }
      __syncthreads();
    }
    if (t == 0) {
      float C[6] = {0.f, 0.f, 0.f, 0.f, 0.f, 0.f};
      const float invM = 1.0f / 524288.0f;
      for (int b = 0; b < 2; ++b) {
        float S0 = acc9[b][0], S1 = acc9[b][1], S2 = acc9[b][2];
        float G00 = acc9[b][3], G01 = acc9[b][4], G02 = acc9[b][5];
        float G11 = acc9[b][6], G12 = acc9[b][7], G22 = acc9[b][8];
        C[0] += 1024.f * G00 - 2.f * S0 * S0;
        C[1] += 1024.f * G01 - 2.f * S0 * S1;
        C[2] += 1024.f * G02 - 2.f * S0 * S2;
        C[3] += 1024.f * G11 - 2.f * S1 * S1;
        C[4] += 1024.f * G12 - 2.f * S1 * S2;
        C[5] += 1024.f * G22 - 2.f * S2 * S2;
      }
      for (int a = 0; a < 6; ++a) C[a] *= invM;
      for (int tt = 0; tt < 3; ++tt) {
        float w0 = Wp1[tt * 3 + 0], w1 = Wp1[tt * 3 + 1], w2 = Wp1[tt * 3 + 2];
        float var = w0 * w0 * C[0] + w1 * w1 * C[3] + w2 * w2 * C[5]
                  + 2.f * (w0 * w1 * C[1] + w0 * w2 * C[2] + w1 * w2 * C[4]);
        a1out[tt] = g_p[tt] * rsqrtf(var + 1e-5f);
      }
      a1out[3] = 0.f;
    }
  }
}

// ---------------------------------------------------------------------------
// K0: q/k/v (fp32 GEMV, transposed weights) + hpa[bn][t] = a1[t]*(Wp1[t].pos)
// ---------------------------------------------------------------------------
__launch_bounds__(256)
__global__ void k0(const float* __restrict__ cf, const float* __restrict__ pos,
                   const float* __restrict__ WqT, const float* __restrict__ WkT,
                   const float* __restrict__ WvT, const float* __restrict__ bq,
                   const float* __restrict__ bk, const float* __restrict__ bv,
                   const float* __restrict__ a1, const float* __restrict__ Wp1,
                   float* __restrict__ qo, float* __restrict__ ko,
                   float* __restrict__ vo, float* __restrict__ hpa) {
  __shared__ float cfl[4][64];
  const int t = threadIdx.x;
  const int r0 = blockIdx.x * 4;
  cfl[t >> 6][t & 63] = cf[(size_t)(r0 + (t >> 6)) * 64 + (t & 63)];
  __syncthreads();
  const int rr = t >> 6, c = t & 63;
  const int bn = r0 + rr;
  float aq = bq[c], ak = bk[c], av = bv[c];
  for (int kk = 0; kk < 64; ++kk) {
    float f = cfl[rr][kk];
    aq = fmaf(f, WqT[kk * 64 + c], aq);
    ak = fmaf(f, WkT[kk * 64 + c], ak);
    av = fmaf(f, WvT[kk * 64 + c], av);
  }
  qo[(size_t)bn * 64 + c] = aq;
  ko[(size_t)bn * 64 + c] = ak;
  vo[(size_t)bn * 64 + c] = av;
  if (t < 16) {
    int rr2 = t >> 2, tt = t & 3;
    int bn2 = r0 + rr2;
    float h = 0.f;
    if (tt < 3) {
      const float* p = pos + (size_t)bn2 * 3;
      h = a1[tt] * (Wp1[tt * 3 + 0] * p[0] + Wp1[tt * 3 + 1] * p[1] + Wp1[tt * 3 + 2] * p[2]);
    }
    hpa[bn2 * 4 + tt] = h;
  }
}

// ---------------------------------------------------------------------------
// K1: BN2 stats pair pass: per-(b,i) block accumulates sum/sumsq of qk per c
// ---------------------------------------------------------------------------
__launch_bounds__(256)
__global__ void k1(const float* __restrict__ q, const float* __restrict__ k,
                   const float* __restrict__ hpa, const float* __restrict__ bp2,
                   const float* __restrict__ Wp2, const float* __restrict__ b_p,
                   float* __restrict__ s1w, float* __restrict__ s2w) {
  const int bid = blockIdx.x;
  const int b = bid >> 9, i = bid & 511;
  const int t = threadIdx.x;
  const int c = t & 63, jq = t >> 6;
  __shared__ __align__(16) float hrl[256][4];
  __shared__ float red[256][2];

  const f32x4 hi = *(const f32x4*)(hpa + (size_t)(b * 512 + i) * 4);
  const float bb0 = b_p[0], bb1 = b_p[1], bb2 = b_p[2];
  const float qb = q[(size_t)(b * 512 + i) * 64 + c] + bp2[c];
  const float w0 = Wp2[c * 3 + 0], w1 = Wp2[c * 3 + 1], w2 = Wp2[c * 3 + 2];
  float s1 = 0.f, s2 = 0.f;

  for (int tile = 0; tile < 2; ++tile) {
    __syncthreads();
    const int j0 = tile * 256;
    {
      const f32x4 hj = *(const f32x4*)(hpa + (size_t)(b * 512 + j0 + t) * 4);
      f32x4 hv;
      hv.x = fmaxf(0.f, hi.x - hj.x + bb0);
      hv.y = fmaxf(0.f, hi.y - hj.y + bb1);
      hv.z = fmaxf(0.f, hi.z - hj.z + bb2);
      hv.w = 0.f;
      *(f32x4*)(&hrl[t][0]) = hv;
    }
    __syncthreads();
    const float* krow = k + (size_t)(b * 512 + j0) * 64;
    for (int jj = 0; jj < 64; ++jj) {
      const int jl = jq * 64 + jj;
      const f32x4 hv = *(const f32x4*)(&hrl[jl][0]);
      const float kv = krow[(size_t)jl * 64 + c];
      float qk = qb - kv;
      qk = fmaf(w0, hv.x, qk);
      qk = fmaf(w1, hv.y, qk);
      qk = fmaf(w2, hv.z, qk);
      s1 += qk;
      s2 = fmaf(qk, qk, s2);
    }
  }
  red[t][0] = s1; red[t][1] = s2;
  __syncthreads();
  if (t < 64) {
    float a = 0.f, bb = 0.f;
#pragma unroll
    for (int p = 0; p < 4; ++p) { a += red[t + 64 * p][0]; bb += red[t + 64 * p][1]; }
    s1w[(size_t)bid * 64 + t] = a;
    s2w[(size_t)bid * 64 + t] = bb;
  }
}

// ---------------------------------------------------------------------------
// K2: reduce partials -> a2, beta2, PtT[t][c] = a2*Wp2col
// ---------------------------------------------------------------------------
__launch_bounds__(256)
__global__ void k2(const float* __restrict__ s1w, const float* __restrict__ s2w,
                   const float* __restrict__ g_w, const float* __restrict__ b_w,
                   const float* __restrict__ Wp2, float* __restrict__ a2o,
                   float* __restrict__ be2o, float* __restrict__ PtT) {
  const int t = threadIdx.x;
  const int c = t & 63, part = t >> 6;
  __shared__ float red[256][2];
  float s1 = 0.f, s2 = 0.f;
  for (int blk = part * 256; blk < (part + 1) * 256; ++blk) {
    s1 += s1w[(size_t)blk * 64 + c];
    s2 += s2w[(size_t)blk * 64 + c];
  }
  red[t][0] = s1; red[t][1] = s2;
  __syncthreads();
  if (t < 64) {
    float a = 0.f, bb = 0.f;
#pragma unroll
    for (int p = 0; p < 4; ++p) { a += red[t + 64 * p][0]; bb += red[t + 64 * p][1]; }
    const float invM = 1.0f / 524288.0f;
    const float mean = a * invM;
    const float var = bb * invM - mean * mean;
    const float rstd = rsqrtf(var + 1e-5f);
    const float a2 = g_w[t] * rstd;
    a2o[t] = a2;
    be2o[t] = b_w[t] - mean * a2;
    PtT[0 * 64 + t] = a2 * Wp2[t * 3 + 0];
    PtT[1 * 64 + t] = a2 * Wp2[t * 3 + 1];
    PtT[2 * 64 + t] = a2 * Wp2[t * 3 + 2];
  }
}

// ---------------------------------------------------------------------------
// K3: fused main kernel. Block=(b,i), 4 waves x 16-j tiles, MFMA GEMMs,
// online softmax over j, out[b,i,c].
// ---------------------------------------------------------------------------
__launch_bounds__(256)
__global__ void k3_main(const float* __restrict__ q, const float* __restrict__ kk_,
                        const float* __restrict__ v, const float* __restrict__ hpa,
                        const float* __restrict__ a2g, const float* __restrict__ be2g,
                        const float* __restrict__ PtTg,
                        const uint16_t* __restrict__ W1bf, const uint16_t* __restrict__ W2bf,
                        const float* __restrict__ bp2, const float* __restrict__ Wp2,
                        const float* __restrict__ b_p, const float* __restrict__ bw1g,
                        const float* __restrict__ bw2g, float* __restrict__ out) {
  const int bid = blockIdx.x;
  const int b = bid >> 9, i = bid & 511;
  const int t = threadIdx.x;
  const int wid = t >> 6, l = t & 63;
  const int lm = l & 15, lq = l >> 4;

  __shared__ __align__(16) float P0[64];
  __shared__ __align__(16) float a2s[64];
  __shared__ __align__(16) float Pts[3][64];
  __shared__ __align__(16) uint16_t H2[4][16][72];
  __shared__ __align__(16) float comb[4][64][3];

  if (t < 64) {
    const float a2v = a2g[t];
    a2s[t] = a2v;
    P0[t] = fmaf(a2v, q[(size_t)(b * 512 + i) * 64 + t] + bp2[t], be2g[t]);
  } else {
    const int idx = t - 64;
    Pts[idx >> 6][idx & 63] = PtTg[idx];
  }

  const f32x4 hi = *(const f32x4*)(hpa + (size_t)(b * 512 + i) * 4);
  const float bb0 = b_p[0], bb1 = b_p[1], bb2 = b_p[2];

  FragU B1[4][2], B2[4][2];
#pragma unroll
  for (int nt = 0; nt < 4; ++nt)
#pragma unroll
    for (int ks = 0; ks < 2; ++ks) {
      const int row = lm + 16 * nt, col = 32 * ks + 8 * lq;
      B1[nt][ks].f = *(const bf16x8*)(W1bf + row * 64 + col);
      B2[nt][ks].f = *(const bf16x8*)(W2bf + row * 64 + col);
    }

  float bw1r[4], bw2r[4], wpa[4], wpb[4], wpc[4], bp2r[4];
#pragma unroll
  for (int nt = 0; nt < 4; ++nt) {
    const int c = 16 * nt + lm;
    bw1r[nt] = bw1g[c];
    bw2r[nt] = bw2g[c];
    wpa[nt] = Wp2[c * 3 + 0];
    wpb[nt] = Wp2[c * 3 + 1];
    wpc[nt] = Wp2[c * 3 + 2];
    bp2r[nt] = bp2[c];
  }

  float m_[4], l_[4], acc_[4];
#pragma unroll
  for (int nt = 0; nt < 4; ++nt) { m_[nt] = -1e30f; l_[nt] = 0.f; acc_[nt] = 0.f; }

  __syncthreads();

  const float LOG2E = 1.4426950408889634f;
  const float* kbase = kk_ + (size_t)(b * 512) * 64;
  const float* vbase = v + (size_t)(b * 512) * 64;
  const float* hbase = hpa + (size_t)(b * 512) * 4;

  for (int it = 0; it < 8; ++it) {
    const int jb = it * 64 + wid * 16;
    const int j = jb + lm;

    // ---- stage A: x = relu(a2*qk + b2) directly as A-fragments ----
    const f32x4 hj = *(const f32x4*)(hbase + j * 4);
    const float h0 = fmaxf(0.f, hi.x - hj.x + bb0);
    const float h1 = fmaxf(0.f, hi.y - hj.y + bb1);
    const float h2v = fmaxf(0.f, hi.z - hj.z + bb2);

    FragU A1[2];
#pragma unroll
    for (int ks = 0; ks < 2; ++ks) {
      const int c0 = 32 * ks + 8 * lq;
      f32x4 pv[2], av[2], t0[2], t1[2], t2[2], kv[2];
      pv[0] = *(const f32x4*)(P0 + c0);        pv[1] = *(const f32x4*)(P0 + c0 + 4);
      av[0] = *(const f32x4*)(a2s + c0);       av[1] = *(const f32x4*)(a2s + c0 + 4);
      t0[0] = *(const f32x4*)(&Pts[0][c0]);    t0[1] = *(const f32x4*)(&Pts[0][c0 + 4]);
      t1[0] = *(const f32x4*)(&Pts[1][c0]);    t1[1] = *(const f32x4*)(&Pts[1][c0 + 4]);
      t2[0] = *(const f32x4*)(&Pts[2][c0]);    t2[1] = *(const f32x4*)(&Pts[2][c0 + 4]);
      kv[0] = *(const f32x4*)(kbase + (size_t)j * 64 + c0);
      kv[1] = *(const f32x4*)(kbase + (size_t)j * 64 + c0 + 4);
      float x[8];
#pragma unroll
      for (int e = 0; e < 8; ++e) {
        const int hh = e >> 2, e4 = e & 3;
        float xv = pv[hh][e4] - av[hh][e4] * kv[hh][e4];
        xv = fmaf(t0[hh][e4], h0, xv);
        xv = fmaf(t1[hh][e4], h1, xv);
        xv = fmaf(t2[hh][e4], h2v, xv);
        x[e] = fmaxf(0.f, xv);
      }
      A1[ks].u[0] = pk_bf16(x[0], x[1]);
      A1[ks].u[1] = pk_bf16(x[2], x[3]);
      A1[ks].u[2] = pk_bf16(x[4], x[5]);
      A1[ks].u[3] = pk_bf16(x[6], x[7]);
    }

    // ---- GEMM1: h2 = x @ Ww1^T ----
    f32x4 d1[4];
#pragma unroll
    for (int nt = 0; nt < 4; ++nt) {
      f32x4 z = {0.f, 0.f, 0.f, 0.f};
      z = __builtin_amdgcn_mfma_f32_16x16x32_bf16(A1[0].f, B1[nt][0].f, z, 0, 0, 0);
      z = __builtin_amdgcn_mfma_f32_16x16x32_bf16(A1[1].f, B1[nt][1].f, z, 0, 0, 0);
      d1[nt] = z;
    }

    // ---- bias+relu, repack h2 to bf16 LDS (per-wave private tile) ----
    uint16_t (*h2w)[72] = H2[wid];
#pragma unroll
    for (int nt = 0; nt < 4; ++nt) {
      const float e0 = fmaxf(0.f, d1[nt][0] + bw1r[nt]);
      const float e1 = fmaxf(0.f, d1[nt][1] + bw1r[nt]);
      const float e2 = fmaxf(0.f, d1[nt][2] + bw1r[nt]);
      const float e3 = fmaxf(0.f, d1[nt][3] + bw1r[nt]);
      const uint32_t u01 = pk_bf16(e0, e1);
      const uint32_t u23 = pk_bf16(e2, e3);
      const int col = 16 * nt + lm;
      h2w[4 * lq + 0][col] = (uint16_t)(u01 & 0xffffu);
      h2w[4 * lq + 1][col] = (uint16_t)(u01 >> 16);
      h2w[4 * lq + 2][col] = (uint16_t)(u23 & 0xffffu);
      h2w[4 * lq + 3][col] = (uint16_t)(u23 >> 16);
    }

    FragU A2[2];
    A2[0].f = *(const bf16x8*)(&h2w[lm][8 * lq]);
    A2[1].f = *(const bf16x8*)(&h2w[lm][32 + 8 * lq]);

    // ---- GEMM2: w = h2 @ Ww2^T ----
    f32x4 d2[4];
#pragma unroll
    for (int nt = 0; nt < 4; ++nt) {
      f32x4 z = {0.f, 0.f, 0.f, 0.f};
      z = __builtin_amdgcn_mfma_f32_16x16x32_bf16(A2[0].f, B2[nt][0].f, z, 0, 0, 0);
      z = __builtin_amdgcn_mfma_f32_16x16x32_bf16(A2[1].f, B2[nt][1].f, z, 0, 0, 0);
      d2[nt] = z;
    }

    // ---- hr for this lane's 4 output j-rows (j = jb + 4*lq + r) ----
    const int j2 = jb + 4 * lq;
    float hr0[4], hr1[4], hr2[4];
#pragma unroll
    for (int r = 0; r < 4; ++r) {
      const f32x4 hjr = *(const f32x4*)(hbase + (j2 + r) * 4);
      hr0[r] = fmaxf(0.f, hi.x - hjr.x + bb0);
      hr1[r] = fmaxf(0.f, hi.y - hjr.y + bb1);
      hr2[r] = fmaxf(0.f, hi.z - hjr.z + bb2);
    }

    // ---- online softmax update ----
#pragma unroll
    for (int nt = 0; nt < 4; ++nt) {
      const int c = 16 * nt + lm;
      float w[4];
#pragma unroll
      for (int r = 0; r < 4; ++r) w[r] = d2[nt][r] + bw2r[nt];
      float tmax = fmaxf(fmaxf(w[0], w[1]), fmaxf(w[2], w[3]));
      tmax = fmaxf(tmax, __shfl_xor(tmax, 16));
      tmax = fmaxf(tmax, __shfl_xor(tmax, 32));
      const float mnew = fmaxf(m_[nt], tmax);
      const float scale = __builtin_amdgcn_exp2f((m_[nt] - mnew) * LOG2E);
      float ps = 0.f, pvs = 0.f;
#pragma unroll
      for (int r = 0; r < 4; ++r) {
        const float p = __builtin_amdgcn_exp2f((w[r] - mnew) * LOG2E);
        float val = vbase[(size_t)(j2 + r) * 64 + c];
        val = fmaf(wpa[nt], hr0[r], val);
        val = fmaf(wpb[nt], hr1[r], val);
        val = fmaf(wpc[nt], hr2[r], val);
        val += bp2r[nt];
        ps += p;
        pvs = fmaf(p, val, pvs);
      }
      ps += __shfl_xor(ps, 16);  ps += __shfl_xor(ps, 32);
      pvs += __shfl_xor(pvs, 16); pvs += __shfl_xor(pvs, 32);
      l_[nt] = fmaf(l_[nt], scale, ps);
      acc_[nt] = fmaf(acc_[nt], scale, pvs);
      m_[nt] = mnew;
    }
  }

  // ---- combine 4 waves' online-softmax states ----
  if (lq == 0) {
#pragma unroll
    for (int nt = 0; nt < 4; ++nt) {
      comb[wid][16 * nt + lm][0] = m_[nt];
      comb[wid][16 * nt + lm][1] = l_[nt];
      comb[wid][16 * nt + lm][2] = acc_[nt];
    }
  }
  __syncthreads();
  if (t < 64) {
    float M = -1e30f;
#pragma unroll
    for (int w = 0; w < 4; ++w) M = fmaxf(M, comb[w][t][0]);
    float L = 0.f, A = 0.f;
#pragma unroll
    for (int w = 0; w < 4; ++w) {
      const float s = __builtin_amdgcn_exp2f((comb[w][t][0] - M) * LOG2E);
      L = fmaf(comb[w][t][1], s, L);
      A = fmaf(comb[w][t][2], s, A);
    }
    out[(size_t)(b * 512 + i) * 64 + t] = A / L;
  }
}

// ---------------------------------------------------------------------------
extern "C" void kernel_launch(void* const* d_in, const int* in_sizes, int n_in,
                              void* d_out, int out_size, void* d_ws, size_t ws_size,
                              hipStream_t stream) {
  (void)in_sizes; (void)n_in; (void)out_size; (void)ws_size;
  const float* pos = (const float*)d_in[0];
  const float* cf  = (const float*)d_in[1];
  const float* Wq  = (const float*)d_in[2];
  const float* bq  = (const float*)d_in[3];
  const float* Wk  = (const float*)d_in[4];
  const float* bk  = (const float*)d_in[5];
  const float* Wv  = (const float*)d_in[6];
  const float* bv  = (const float*)d_in[7];
  const float* Wp1 = (const float*)d_in[8];
  // d_in[9] = bp1: cancels analytically (gamma1 == b_p exactly)
  const float* g_p = (const float*)d_in[10];
  const float* b_p = (const float*)d_in[11];
  const float* Wp2 = (const float*)d_in[12];
  const float* bp2 = (const float*)d_in[13];
  const float* g_w = (const float*)d_in[14];
  const float* b_w = (const float*)d_in[15];
  const float* Ww1 = (const float*)d_in[16];
  const float* bw1 = (const float*)d_in[17];
  const float* Ww2 = (const float*)d_in[18];
  const float* bw2 = (const float*)d_in[19];

  char* ws = (char*)d_ws;
  float*    WqT  = (float*)(ws + 0);
  float*    WkT  = (float*)(ws + 16384);
  float*    WvT  = (float*)(ws + 32768);
  uint16_t* W1bf = (uint16_t*)(ws + 49152);
  uint16_t* W2bf = (uint16_t*)(ws + 57344);
  float*    a1w  = (float*)(ws + 65536);
  float*    hpaw = (float*)(ws + 66560);    // [2*512][4]
  float*    qw   = (float*)(ws + 83968);    // [1024][64]
  float*    kw   = (float*)(ws + 347136);
  float*    vw   = (float*)(ws + 610304);
  float*    s1w  = (float*)(ws + 873472);   // [1024][64]
  float*    s2w  = (float*)(ws + 1136640);
  float*    a2w  = (float*)(ws + 1399808);
  float*    be2w = (float*)(ws + 1400064);
  float*    PtTw = (float*)(ws + 1400320);  // [3][64]

  kpre<<<dim3(5), dim3(256), 0, stream>>>(Wq, Wk, Wv, Ww1, Ww2, pos, Wp1, g_p,
                                          WqT, WkT, WvT, W1bf, W2bf, a1w);
  k0<<<dim3(256), dim3(256), 0, stream>>>(cf, pos, WqT, WkT, WvT, bq, bk, bv,
                                          a1w, Wp1, qw, kw, vw, hpaw);
  k1<<<dim3(1024), dim3(256), 0, stream>>>(qw, kw, hpaw, bp2, Wp2, b_p, s1w, s2w);
  k2<<<dim3(1), dim3(256), 0, stream>>>(s1w, s2w, g_w, b_w, Wp2, a2w, be2w, PtTw);
  k3_main<<<dim3(1024), dim3(256), 0, stream>>>(qw, kw, vw, hpaw, a2w, be2w, PtTw,
                                                W1bf, W2bf, bp2, Wp2, b_p, bw1, bw2,
                                                (float*)d_out);
}

// Round 2
// 129.446 us; speedup vs baseline: 1.5677x; 1.5677x over previous
//
#include <hip/hip_runtime.h>
#include <stdint.h>
#include <stddef.h>

#define DEV __device__ __forceinline__

typedef __attribute__((ext_vector_type(4))) float f32x4;
typedef __attribute__((ext_vector_type(8))) short bf16x8;

union FragU { bf16x8 f; uint32_t u[4]; };

DEV uint32_t pk_bf16(float a, float b) {
  uint32_t d;
  asm("v_cvt_pk_bf16_f32 %0, %1, %2" : "=v"(d) : "v"(a), "v"(b));
  return d;
}

DEV uint16_t f2bf(float x) {  // round-to-nearest-even
  uint32_t u = __float_as_uint(x);
  u += 0x7fffu + ((u >> 16) & 1u);
  return (uint16_t)(u >> 16);
}

// ---------------------------------------------------------------------------
// K_pre: blocks 0..2: transpose Wq/Wk/Wv; block 3: Ww1/Ww2 -> bf16;
//        block 4: analytic BN1 stats -> a1[t] = g_p*rsqrt(var+eps)
// ---------------------------------------------------------------------------
__launch_bounds__(256)
__global__ void kpre(const float* __restrict__ Wq, const float* __restrict__ Wk,
                     const float* __restrict__ Wv, const float* __restrict__ Ww1,
                     const float* __restrict__ Ww2, const float* __restrict__ pos,
                     const float* __restrict__ Wp1, const float* __restrict__ g_p,
                     float* __restrict__ WqT, float* __restrict__ WkT,
                     float* __restrict__ WvT, uint16_t* __restrict__ W1bf,
                     uint16_t* __restrict__ W2bf, float* __restrict__ a1out) {
  const int bid = blockIdx.x, t = threadIdx.x;
  if (bid < 3) {
    const float* src = (bid == 0) ? Wq : ((bid == 1) ? Wk : Wv);
    float* dst = (bid == 0) ? WqT : ((bid == 1) ? WkT : WvT);
    for (int idx = t; idx < 4096; idx += 256) {
      int kk = idx >> 6, c = idx & 63;
      dst[kk * 64 + c] = src[c * 64 + kk];
    }
  } else if (bid == 3) {
    for (int idx = t; idx < 8192; idx += 256) {
      if (idx < 4096) W1bf[idx] = f2bf(Ww1[idx]);
      else            W2bf[idx - 4096] = f2bf(Ww2[idx - 4096]);
    }
  } else {
    __shared__ float acc9[2][9];
    __shared__ float red[256][10];
    for (int b = 0; b < 2; ++b) {
      float s[9];
#pragma unroll
      for (int a = 0; a < 9; ++a) s[a] = 0.f;
      for (int r = 0; r < 2; ++r) {
        int i = t + 256 * r;
        const float* p = pos + (size_t)(b * 512 + i) * 3;
        float p0 = p[0], p1 = p[1], p2 = p[2];
        s[0] += p0; s[1] += p1; s[2] += p2;
        s[3] += p0 * p0; s[4] += p0 * p1; s[5] += p0 * p2;
        s[6] += p1 * p1; s[7] += p1 * p2; s[8] += p2 * p2;
      }
#pragma unroll
      for (int a = 0; a < 9; ++a) red[t][a] = s[a];
      __syncthreads();
      if (t < 9) {
        float vsum = 0.f;
        for (int qq = 0; qq < 256; ++qq) vsum += red[qq][t];
        acc9[b][t] = vsum;
      }
      __syncthreads();
    }
    if (t == 0) {
      float C[6] = {0.f, 0.f, 0.f, 0.f, 0.f, 0.f};
      const float invM = 1.0f / 524288.0f;
      for (int b = 0; b < 2; ++b) {
        float S0 = acc9[b][0], S1 = acc9[b][1], S2 = acc9[b][2];
        float G00 = acc9[b][3], G01 = acc9[b][4], G02 = acc9[b][5];
        float G11 = acc9[b][6], G12 = acc9[b][7], G22 = acc9[b][8];
        C[0] += 1024.f * G00 - 2.f * S0 * S0;
        C[1] += 1024.f * G01 - 2.f * S0 * S1;
        C[2] += 1024.f * G02 - 2.f * S0 * S2;
        C[3] += 1024.f * G11 - 2.f * S1 * S1;
        C[4] += 1024.f * G12 - 2.f * S1 * S2;
        C[5] += 1024.f * G22 - 2.f * S2 * S2;
      }
      for (int a = 0; a < 6; ++a) C[a] *= invM;
      for (int tt = 0; tt < 3; ++tt) {
        float w0 = Wp1[tt * 3 + 0], w1 = Wp1[tt * 3 + 1], w2 = Wp1[tt * 3 + 2];
        float var = w0 * w0 * C[0] + w1 * w1 * C[3] + w2 * w2 * C[5]
                  + 2.f * (w0 * w1 * C[1] + w0 * w2 * C[2] + w1 * w2 * C[4]);
        a1out[tt] = g_p[tt] * rsqrtf(var + 1e-5f);
      }
      a1out[3] = 0.f;
    }
  }
}

// ---------------------------------------------------------------------------
// K0: q/k (row-major), v transposed (vT[b][c][n]), hpa[bn][t]=a1[t]*(Wp1[t].pos)
// ---------------------------------------------------------------------------
__launch_bounds__(256)
__global__ void k0(const float* __restrict__ cf, const float* __restrict__ pos,
                   const float* __restrict__ WqT, const float* __restrict__ WkT,
                   const float* __restrict__ WvT, const float* __restrict__ bq,
                   const float* __restrict__ bk, const float* __restrict__ bv,
                   const float* __restrict__ a1, const float* __restrict__ Wp1,
                   float* __restrict__ qo, float* __restrict__ ko,
                   float* __restrict__ vT, float* __restrict__ hpa) {
  __shared__ float cfl[4][64];
  const int t = threadIdx.x;
  const int r0 = blockIdx.x * 4;
  cfl[t >> 6][t & 63] = cf[(size_t)(r0 + (t >> 6)) * 64 + (t & 63)];
  __syncthreads();
  const int rr = t >> 6, c = t & 63;
  const int bn = r0 + rr;
  float aq = bq[c], ak = bk[c], av = bv[c];
  for (int kk = 0; kk < 64; ++kk) {
    float f = cfl[rr][kk];
    aq = fmaf(f, WqT[kk * 64 + c], aq);
    ak = fmaf(f, WkT[kk * 64 + c], ak);
    av = fmaf(f, WvT[kk * 64 + c], av);
  }
  qo[(size_t)bn * 64 + c] = aq;
  ko[(size_t)bn * 64 + c] = ak;
  vT[((size_t)(bn >> 9) * 64 + c) * 512 + (bn & 511)] = av;
  if (t < 16) {
    int rr2 = t >> 2, tt = t & 3;
    int bn2 = r0 + rr2;
    float h = 0.f;
    if (tt < 3) {
      const float* p = pos + (size_t)bn2 * 3;
      h = a1[tt] * (Wp1[tt * 3 + 0] * p[0] + Wp1[tt * 3 + 1] * p[1] + Wp1[tt * 3 + 2] * p[2]);
    }
    hpa[bn2 * 4 + tt] = h;
  }
}

// ---------------------------------------------------------------------------
// K1n: bid<32: 3-channel pair pass over hpa -> R_t(i) (sign 0) / C_t(j)
//      (sign 1) + M_tu partials (sign 0). bid 32/33: per-batch N-pass
//      moments of u=q+bp2 and k.
// ---------------------------------------------------------------------------
__launch_bounds__(256)
__global__ void k1n(const float* __restrict__ hpa, const float* __restrict__ b_p,
                    const float* __restrict__ q, const float* __restrict__ k,
                    const float* __restrict__ bp2,
                    float* __restrict__ Rw, float* __restrict__ Cw,
                    float* __restrict__ Mpart, float* __restrict__ SN) {
  const int bid = blockIdx.x, t = threadIdx.x;
  if (bid < 32) {
    const int s = bid >> 4, b = (bid >> 3) & 1, chunk = bid & 7;
    __shared__ __align__(16) f32x4 X[512];
    __shared__ float redr[64][4][4];
    __shared__ float mred[256][6];
    __shared__ float mred2[64][6];
    for (int r = 0; r < 2; ++r) {
      int row = t + 256 * r;
      f32x4 v = *(const f32x4*)(hpa + (size_t)(b * 512 + row) * 4);
      if (s) { v.x = -v.x; v.y = -v.y; v.z = -v.z; }
      X[row] = v;
    }
    __syncthreads();
    const int al = t >> 2, qr = t & 3;
    const int a = chunk * 64 + al;
    const f32x4 xa = X[a];
    const float base0 = xa.x + b_p[0], base1 = xa.y + b_p[1], base2 = xa.z + b_p[2];
    float r0 = 0, r1 = 0, r2 = 0;
    float m00 = 0, m01 = 0, m02 = 0, m11 = 0, m12 = 0, m22 = 0;
    for (int jj = qr * 128; jj < qr * 128 + 128; ++jj) {
      const f32x4 xj = X[jj];
      const float h0 = fmaxf(0.f, base0 - xj.x);
      const float h1 = fmaxf(0.f, base1 - xj.y);
      const float h2 = fmaxf(0.f, base2 - xj.z);
      r0 += h0; r1 += h1; r2 += h2;
      if (s == 0) {
        m00 = fmaf(h0, h0, m00); m01 = fmaf(h0, h1, m01); m02 = fmaf(h0, h2, m02);
        m11 = fmaf(h1, h1, m11); m12 = fmaf(h1, h2, m12); m22 = fmaf(h2, h2, m22);
      }
    }
    redr[al][qr][0] = r0; redr[al][qr][1] = r1; redr[al][qr][2] = r2; redr[al][qr][3] = 0.f;
    mred[t][0] = m00; mred[t][1] = m01; mred[t][2] = m02;
    mred[t][3] = m11; mred[t][4] = m12; mred[t][5] = m22;
    __syncthreads();
    if (t < 64) {
      float sx = 0, sy = 0, sz = 0;
#pragma unroll
      for (int p = 0; p < 4; ++p) { sx += redr[t][p][0]; sy += redr[t][p][1]; sz += redr[t][p][2]; }
      float* dst = (s ? Cw : Rw) + (size_t)(b * 512 + chunk * 64 + t) * 4;
      dst[0] = sx; dst[1] = sy; dst[2] = sz; dst[3] = 0.f;
      if (s == 0) {
#pragma unroll
        for (int cc = 0; cc < 6; ++cc)
          mred2[t][cc] = mred[t][cc] + mred[t + 64][cc] + mred[t + 128][cc] + mred[t + 192][cc];
      }
    }
    __syncthreads();
    if (s == 0 && t < 6) {
      float m = 0.f;
      for (int p = 0; p < 64; ++p) m += mred2[p][t];
      Mpart[bid * 8 + t] = m;
    }
  } else {
    const int b = bid - 32;
    __shared__ float redn[256][4];
    const int c = t & 63, g = t >> 6;
    float su = 0, su2 = 0, sk = 0, sk2 = 0;
    const float bp = bp2[c];
    for (int i = g * 128; i < g * 128 + 128; ++i) {
      const float uq = q[(size_t)(b * 512 + i) * 64 + c] + bp;
      const float kv = k[(size_t)(b * 512 + i) * 64 + c];
      su += uq; su2 = fmaf(uq, uq, su2);
      sk += kv; sk2 = fmaf(kv, kv, sk2);
    }
    redn[t][0] = su; redn[t][1] = su2; redn[t][2] = sk; redn[t][3] = sk2;
    __syncthreads();
    if (t < 64) {
      float a0 = 0, a1 = 0, a2 = 0, a3 = 0;
#pragma unroll
      for (int p = 0; p < 4; ++p) {
        a0 += redn[t + 64 * p][0]; a1 += redn[t + 64 * p][1];
        a2 += redn[t + 64 * p][2]; a3 += redn[t + 64 * p][3];
      }
      SN[(b * 4 + 0) * 64 + t] = a0;
      SN[(b * 4 + 1) * 64 + t] = a1;
      SN[(b * 4 + 2) * 64 + t] = a2;
      SN[(b * 4 + 3) * 64 + t] = a3;
    }
  }
}

// ---------------------------------------------------------------------------
// K2n: assemble BN2 stats analytically -> a2, be2, PtT
// ---------------------------------------------------------------------------
__launch_bounds__(256)
__global__ void k2n(const float* __restrict__ q, const float* __restrict__ k,
                    const float* __restrict__ bp2,
                    const float* __restrict__ Rw, const float* __restrict__ Cw,
                    const float* __restrict__ Mpart, const float* __restrict__ SN,
                    const float* __restrict__ g_w, const float* __restrict__ b_w,
                    const float* __restrict__ Wp2,
                    float* __restrict__ a2o, float* __restrict__ be2o,
                    float* __restrict__ PtT) {
  const int t = threadIdx.x;
  const int c = t & 63, g = t >> 6;
  __shared__ float red[256][12];
  __shared__ float shs[4][3];
  __shared__ float Mf[6];
  __shared__ float Shf[3];
  float ur[2][3] = {{0,0,0},{0,0,0}}, kc[2][3] = {{0,0,0},{0,0,0}};
  float shp0 = 0, shp1 = 0, shp2 = 0;
  const float bp = bp2[c];
  for (int b = 0; b < 2; ++b) {
    for (int i = g * 128; i < g * 128 + 128; ++i) {
      const size_t row = (size_t)(b * 512 + i);
      const float uq = q[row * 64 + c] + bp;
      const float kv = k[row * 64 + c];
      const f32x4 rv = *(const f32x4*)(Rw + row * 4);
      const f32x4 cv = *(const f32x4*)(Cw + row * 4);
      ur[b][0] = fmaf(uq, rv.x, ur[b][0]);
      ur[b][1] = fmaf(uq, rv.y, ur[b][1]);
      ur[b][2] = fmaf(uq, rv.z, ur[b][2]);
      kc[b][0] = fmaf(kv, cv.x, kc[b][0]);
      kc[b][1] = fmaf(kv, cv.y, kc[b][1]);
      kc[b][2] = fmaf(kv, cv.z, kc[b][2]);
      if (c == 0) { shp0 += rv.x; shp1 += rv.y; shp2 += rv.z; }
    }
  }
#pragma unroll
  for (int b = 0; b < 2; ++b)
#pragma unroll
    for (int tt = 0; tt < 3; ++tt) {
      red[t][b * 3 + tt] = ur[b][tt];
      red[t][6 + b * 3 + tt] = kc[b][tt];
    }
  if (c == 0) { shs[g][0] = shp0; shs[g][1] = shp1; shs[g][2] = shp2; }
  __syncthreads();
  if (t < 6) {
    float m = 0.f;
    for (int p = 0; p < 16; ++p) m += Mpart[p * 8 + t];
    Mf[t] = m;
  }
  if (t < 3) Shf[t] = shs[0][t] + shs[1][t] + shs[2][t] + shs[3][t];
  __syncthreads();
  if (t < 64) {
    float UR[2][3], KC[2][3];
#pragma unroll
    for (int b = 0; b < 2; ++b)
#pragma unroll
      for (int tt = 0; tt < 3; ++tt) {
        float su = 0, sk = 0;
#pragma unroll
        for (int p = 0; p < 4; ++p) {
          su += red[t + 64 * p][b * 3 + tt];
          sk += red[t + 64 * p][6 + b * 3 + tt];
        }
        UR[b][tt] = su; KC[b][tt] = sk;
      }
    const float P0t = Wp2[t * 3 + 0], P1t = Wp2[t * 3 + 1], P2t = Wp2[t * 3 + 2];
    const float Nf = 512.f, invM = 1.f / 524288.f;
    float S1 = 0.f, Q2 = 0.f, Xc = 0.f;
#pragma unroll
    for (int b = 0; b < 2; ++b) {
      const float Su = SN[(b * 4 + 0) * 64 + t];
      const float Su2 = SN[(b * 4 + 1) * 64 + t];
      const float Sk = SN[(b * 4 + 2) * 64 + t];
      const float Sk2 = SN[(b * 4 + 3) * 64 + t];
      S1 += Nf * (Su - Sk);
      Q2 += Nf * Su2 - 2.f * Su * Sk + Nf * Sk2;
      Xc += P0t * (UR[b][0] - KC[b][0]) + P1t * (UR[b][1] - KC[b][1]) + P2t * (UR[b][2] - KC[b][2]);
    }
    S1 += P0t * Shf[0] + P1t * Shf[1] + P2t * Shf[2];
    const float Hm = P0t * P0t * Mf[0] + 2.f * P0t * P1t * Mf[1] + 2.f * P0t * P2t * Mf[2]
                   + P1t * P1t * Mf[3] + 2.f * P1t * P2t * Mf[4] + P2t * P2t * Mf[5];
    const float E1 = S1 * invM;
    const float E2 = (Q2 + 2.f * Xc + Hm) * invM;
    const float var = E2 - E1 * E1;
    const float rstd = rsqrtf(var + 1e-5f);
    const float A2 = g_w[t] * rstd;
    a2o[t] = A2;
    be2o[t] = b_w[t] - E1 * A2;
    PtT[0 * 64 + t] = A2 * P0t;
    PtT[1 * 64 + t] = A2 * P1t;
    PtT[2 * 64 + t] = A2 * P2t;
  }
}

// ---------------------------------------------------------------------------
// K3: fused main. Block=(b,i), 4 waves x 16-j tiles, per-lane online softmax
// (no in-loop cross-lane ops), weights in padded LDS, prefetched loads.
// ---------------------------------------------------------------------------
__launch_bounds__(256, 3)
__global__ void k3_main(const float* __restrict__ q, const float* __restrict__ kk_,
                        const float* __restrict__ vT, const float* __restrict__ hpa,
                        const float* __restrict__ a2g, const float* __restrict__ be2g,
                        const float* __restrict__ PtTg,
                        const uint16_t* __restrict__ W1bf, const uint16_t* __restrict__ W2bf,
                        const float* __restrict__ bp2, const float* __restrict__ Wp2,
                        const float* __restrict__ b_p, const float* __restrict__ bw1g,
                        const float* __restrict__ bw2g, float* __restrict__ out) {
  const int bid = blockIdx.x;
  const int b = bid >> 9, i = bid & 511;
  const int t = threadIdx.x;
  const int wid = t >> 6, l = t & 63;
  const int lm = l & 15, lq = l >> 4;

  __shared__ __align__(16) float P0[64];
  __shared__ __align__(16) float a2s[64];
  __shared__ __align__(16) float Pts[3][64];
  __shared__ __align__(16) uint16_t H2[4][16][72];
  __shared__ __align__(16) uint16_t W1l[64][72];
  __shared__ __align__(16) uint16_t W2l[64][72];
  __shared__ __align__(16) float comb[16][64][3];

  {
    const int base = t * 16;
#pragma unroll
    for (int e = 0; e < 16; ++e) {
      const int idx = base + e;
      const int row = idx >> 6, col = idx & 63;
      W1l[row][col] = W1bf[idx];
      W2l[row][col] = W2bf[idx];
    }
  }
  if (t < 64) {
    const float a2v = a2g[t];
    a2s[t] = a2v;
    P0[t] = fmaf(a2v, q[(size_t)(b * 512 + i) * 64 + t] + bp2[t], be2g[t]);
  } else {
    const int idx = t - 64;
    Pts[idx >> 6][idx & 63] = PtTg[idx];
  }

  const f32x4 hi = *(const f32x4*)(hpa + (size_t)(b * 512 + i) * 4);
  const float bb0 = b_p[0], bb1 = b_p[1], bb2 = b_p[2];

  float bw1r[4], bw2r[4], wpa[4], wpb[4], wpc[4], bp2r[4];
#pragma unroll
  for (int nt = 0; nt < 4; ++nt) {
    const int c = 16 * nt + lm;
    bw1r[nt] = bw1g[c];
    bw2r[nt] = bw2g[c];
    wpa[nt] = Wp2[c * 3 + 0];
    wpb[nt] = Wp2[c * 3 + 1];
    wpc[nt] = Wp2[c * 3 + 2];
    bp2r[nt] = bp2[c];
  }

  float m_[4], l_[4], acc_[4];
#pragma unroll
  for (int nt = 0; nt < 4; ++nt) { m_[nt] = -1e30f; l_[nt] = 0.f; acc_[nt] = 0.f; }

  __syncthreads();

  const float LOG2E = 1.4426950408889634f;
  const float* kbase = kk_ + (size_t)(b * 512) * 64;
  const float* hbase = hpa + (size_t)(b * 512) * 4;
  const float* vTb = vT + (size_t)b * 64 * 512;

  for (int it = 0; it < 8; ++it) {
    const int jb = it * 64 + wid * 16;
    const int j = jb + lm;
    const int j2 = jb + 4 * lq;

    // ---- issue ALL global loads for this iteration up front ----
    f32x4 kv[2][2];
#pragma unroll
    for (int ks = 0; ks < 2; ++ks) {
      kv[ks][0] = *(const f32x4*)(kbase + (size_t)j * 64 + 32 * ks + 8 * lq);
      kv[ks][1] = *(const f32x4*)(kbase + (size_t)j * 64 + 32 * ks + 8 * lq + 4);
    }
    const f32x4 hj = *(const f32x4*)(hbase + j * 4);
    f32x4 hjr[4];
#pragma unroll
    for (int r = 0; r < 4; ++r) hjr[r] = *(const f32x4*)(hbase + (j2 + r) * 4);
    f32x4 vv[4];
#pragma unroll
    for (int nt = 0; nt < 4; ++nt)
      vv[nt] = *(const f32x4*)(vTb + (size_t)(16 * nt + lm) * 512 + j2);

    // ---- stage A: x = relu(a2*qk + b2) as A-fragments ----
    const float h0 = fmaxf(0.f, hi.x - hj.x + bb0);
    const float h1 = fmaxf(0.f, hi.y - hj.y + bb1);
    const float h2v = fmaxf(0.f, hi.z - hj.z + bb2);

    FragU A1[2];
#pragma unroll
    for (int ks = 0; ks < 2; ++ks) {
      const int c0 = 32 * ks + 8 * lq;
      f32x4 pv[2], av[2], t0[2], t1[2], t2[2];
      pv[0] = *(const f32x4*)(P0 + c0);        pv[1] = *(const f32x4*)(P0 + c0 + 4);
      av[0] = *(const f32x4*)(a2s + c0);       av[1] = *(const f32x4*)(a2s + c0 + 4);
      t0[0] = *(const f32x4*)(&Pts[0][c0]);    t0[1] = *(const f32x4*)(&Pts[0][c0 + 4]);
      t1[0] = *(const f32x4*)(&Pts[1][c0]);    t1[1] = *(const f32x4*)(&Pts[1][c0 + 4]);
      t2[0] = *(const f32x4*)(&Pts[2][c0]);    t2[1] = *(const f32x4*)(&Pts[2][c0 + 4]);
      float x[8];
#pragma unroll
      for (int e = 0; e < 8; ++e) {
        const int hh = e >> 2, e4 = e & 3;
        float xv = pv[hh][e4] - av[hh][e4] * kv[ks][hh][e4];
        xv = fmaf(t0[hh][e4], h0, xv);
        xv = fmaf(t1[hh][e4], h1, xv);
        xv = fmaf(t2[hh][e4], h2v, xv);
        x[e] = fmaxf(0.f, xv);
      }
      A1[ks].u[0] = pk_bf16(x[0], x[1]);
      A1[ks].u[1] = pk_bf16(x[2], x[3]);
      A1[ks].u[2] = pk_bf16(x[4], x[5]);
      A1[ks].u[3] = pk_bf16(x[6], x[7]);
    }

    // ---- GEMM1: h2 = x @ Ww1^T (B-frags from LDS) ----
    f32x4 d1[4];
#pragma unroll
    for (int nt = 0; nt < 4; ++nt) {
      FragU b0, b1;
      b0.f = *(const bf16x8*)(&W1l[16 * nt + lm][8 * lq]);
      b1.f = *(const bf16x8*)(&W1l[16 * nt + lm][32 + 8 * lq]);
      f32x4 z = {0.f, 0.f, 0.f, 0.f};
      z = __builtin_amdgcn_mfma_f32_16x16x32_bf16(A1[0].f, b0.f, z, 0, 0, 0);
      z = __builtin_amdgcn_mfma_f32_16x16x32_bf16(A1[1].f, b1.f, z, 0, 0, 0);
      d1[nt] = z;
    }

    // ---- bias+relu, repack h2 to bf16 LDS (per-wave private tile) ----
    uint16_t (*h2w)[72] = H2[wid];
#pragma unroll
    for (int nt = 0; nt < 4; ++nt) {
      const float e0 = fmaxf(0.f, d1[nt][0] + bw1r[nt]);
      const float e1 = fmaxf(0.f, d1[nt][1] + bw1r[nt]);
      const float e2 = fmaxf(0.f, d1[nt][2] + bw1r[nt]);
      const float e3 = fmaxf(0.f, d1[nt][3] + bw1r[nt]);
      const uint32_t u01 = pk_bf16(e0, e1);
      const uint32_t u23 = pk_bf16(e2, e3);
      const int col = 16 * nt + lm;
      h2w[4 * lq + 0][col] = (uint16_t)(u01 & 0xffffu);
      h2w[4 * lq + 1][col] = (uint16_t)(u01 >> 16);
      h2w[4 * lq + 2][col] = (uint16_t)(u23 & 0xffffu);
      h2w[4 * lq + 3][col] = (uint16_t)(u23 >> 16);
    }

    FragU A2[2];
    A2[0].f = *(const bf16x8*)(&h2w[lm][8 * lq]);
    A2[1].f = *(const bf16x8*)(&h2w[lm][32 + 8 * lq]);

    // ---- GEMM2: w = h2 @ Ww2^T (B-frags from LDS) ----
    f32x4 d2[4];
#pragma unroll
    for (int nt = 0; nt < 4; ++nt) {
      FragU b0, b1;
      b0.f = *(const bf16x8*)(&W2l[16 * nt + lm][8 * lq]);
      b1.f = *(const bf16x8*)(&W2l[16 * nt + lm][32 + 8 * lq]);
      f32x4 z = {0.f, 0.f, 0.f, 0.f};
      z = __builtin_amdgcn_mfma_f32_16x16x32_bf16(A2[0].f, b0.f, z, 0, 0, 0);
      z = __builtin_amdgcn_mfma_f32_16x16x32_bf16(A2[1].f, b1.f, z, 0, 0, 0);
      d2[nt] = z;
    }

    // ---- hr for this lane's 4 output j-rows ----
    float hr0[4], hr1[4], hr2[4];
#pragma unroll
    for (int r = 0; r < 4; ++r) {
      hr0[r] = fmaxf(0.f, hi.x - hjr[r].x + bb0);
      hr1[r] = fmaxf(0.f, hi.y - hjr[r].y + bb1);
      hr2[r] = fmaxf(0.f, hi.z - hjr[r].z + bb2);
    }

    // ---- per-lane online softmax update (no cross-lane ops) ----
#pragma unroll
    for (int nt = 0; nt < 4; ++nt) {
      float w[4];
#pragma unroll
      for (int r = 0; r < 4; ++r) w[r] = d2[nt][r] + bw2r[nt];
      const float tmax = fmaxf(fmaxf(w[0], w[1]), fmaxf(w[2], w[3]));
      const float mnew = fmaxf(m_[nt], tmax);
      const float scale = __builtin_amdgcn_exp2f((m_[nt] - mnew) * LOG2E);
      float ps = 0.f, pvs = 0.f;
#pragma unroll
      for (int r = 0; r < 4; ++r) {
        const float p = __builtin_amdgcn_exp2f((w[r] - mnew) * LOG2E);
        float val = vv[nt][r];
        val = fmaf(wpa[nt], hr0[r], val);
        val = fmaf(wpb[nt], hr1[r], val);
        val = fmaf(wpc[nt], hr2[r], val);
        val += bp2r[nt];
        ps += p;
        pvs = fmaf(p, val, pvs);
      }
      l_[nt] = fmaf(l_[nt], scale, ps);
      acc_[nt] = fmaf(acc_[nt], scale, pvs);
      m_[nt] = mnew;
    }
  }

  // ---- combine 16 per-lane-group states ----
  {
    const int gidx = wid * 4 + lq;
#pragma unroll
    for (int nt = 0; nt < 4; ++nt) {
      comb[gidx][16 * nt + lm][0] = m_[nt];
      comb[gidx][16 * nt + lm][1] = l_[nt];
      comb[gidx][16 * nt + lm][2] = acc_[nt];
    }
  }
  __syncthreads();
  if (t < 64) {
    float M = -1e30f;
#pragma unroll
    for (int g = 0; g < 16; ++g) M = fmaxf(M, comb[g][t][0]);
    float L = 0.f, A = 0.f;
#pragma unroll
    for (int g = 0; g < 16; ++g) {
      const float s = __builtin_amdgcn_exp2f((comb[g][t][0] - M) * LOG2E);
      L = fmaf(comb[g][t][1], s, L);
      A = fmaf(comb[g][t][2], s, A);
    }
    out[(size_t)(b * 512 + i) * 64 + t] = A / L;
  }
}

// ---------------------------------------------------------------------------
extern "C" void kernel_launch(void* const* d_in, const int* in_sizes, int n_in,
                              void* d_out, int out_size, void* d_ws, size_t ws_size,
                              hipStream_t stream) {
  (void)in_sizes; (void)n_in; (void)out_size; (void)ws_size;
  const float* pos = (const float*)d_in[0];
  const float* cf  = (const float*)d_in[1];
  const float* Wq  = (const float*)d_in[2];
  const float* bq  = (const float*)d_in[3];
  const float* Wk  = (const float*)d_in[4];
  const float* bk  = (const float*)d_in[5];
  const float* Wv  = (const float*)d_in[6];
  const float* bv  = (const float*)d_in[7];
  const float* Wp1 = (const float*)d_in[8];
  // d_in[9] = bp1: cancels analytically (gamma1 == b_p exactly)
  const float* g_p = (const float*)d_in[10];
  const float* b_p = (const float*)d_in[11];
  const float* Wp2 = (const float*)d_in[12];
  const float* bp2 = (const float*)d_in[13];
  const float* g_w = (const float*)d_in[14];
  const float* b_w = (const float*)d_in[15];
  const float* Ww1 = (const float*)d_in[16];
  const float* bw1 = (const float*)d_in[17];
  const float* Ww2 = (const float*)d_in[18];
  const float* bw2 = (const float*)d_in[19];

  char* ws = (char*)d_ws;
  float*    WqT  = (float*)(ws + 0);
  float*    WkT  = (float*)(ws + 16384);
  float*    WvT  = (float*)(ws + 32768);
  uint16_t* W1bf = (uint16_t*)(ws + 49152);
  uint16_t* W2bf = (uint16_t*)(ws + 57344);
  float*    a1w  = (float*)(ws + 65536);
  float*    hpaw = (float*)(ws + 66560);    // [1024][4]
  float*    qw   = (float*)(ws + 83968);    // [1024][64]
  float*    kw   = (float*)(ws + 347136);   // [1024][64]
  float*    vTw  = (float*)(ws + 610304);   // [2][64][512]
  float*    Rww  = (float*)(ws + 873472);   // [1024][4]
  float*    Cww  = (float*)(ws + 890880);   // [1024][4]
  float*    Mpw  = (float*)(ws + 907264);   // [16][8]
  float*    SNw  = (float*)(ws + 908288);   // [2][4][64]
  float*    a2w  = (float*)(ws + 911360);
  float*    be2w = (float*)(ws + 911616);
  float*    PtTw = (float*)(ws + 911872);   // [3][64]

  kpre<<<dim3(5), dim3(256), 0, stream>>>(Wq, Wk, Wv, Ww1, Ww2, pos, Wp1, g_p,
                                          WqT, WkT, WvT, W1bf, W2bf, a1w);
  k0<<<dim3(256), dim3(256), 0, stream>>>(cf, pos, WqT, WkT, WvT, bq, bk, bv,
                                          a1w, Wp1, qw, kw, vTw, hpaw);
  k1n<<<dim3(34), dim3(256), 0, stream>>>(hpaw, b_p, qw, kw, bp2, Rww, Cww, Mpw, SNw);
  k2n<<<dim3(1), dim3(256), 0, stream>>>(qw, kw, bp2, Rww, Cww, Mpw, SNw,
                                         g_w, b_w, Wp2, a2w, be2w, PtTw);
  k3_main<<<dim3(1024), dim3(256), 0, stream>>>(qw, kw, vTw, hpaw, a2w, be2w, PtTw,
                                                W1bf, W2bf, bp2, Wp2, b_p, bw1, bw2,
                                                (float*)d_out);
}